// Round 10
// baseline (148.562 us; speedup 1.0000x reference)
//
#include <hip/hip_runtime.h>

#define B_   256
#define I_   1152
#define N_   10
#define P_   9216      // 8 * 1152
#define NO_  160       // 10 * 16

typedef unsigned short u16;
typedef short s8v __attribute__((ext_vector_type(8)));
typedef float f4v __attribute__((ext_vector_type(4)));

__device__ inline float bf2f(u16 u){
  unsigned v = ((unsigned)u) << 16; float f; __builtin_memcpy(&f, &v, 4); return f;
}
__device__ inline u16 f2bf(float f){
  unsigned b; __builtin_memcpy(&b, &f, 4);
  b += 0x7fffu + ((b >> 16) & 1u);   // RNE
  return (u16)(b >> 16);
}

// ---------------------------------------------------------------------------
// k_prep: grid 3104 x 256.
//   blocks [0,800):  W-part, one (q, i-chunk-of-256) per block (was 160 blocks
//                    looping 4.5 chunks — long-pole tail). q = u/5, ic = u%5.
//                    Wt[q=n*16+o][p=k*1152+i] = bf16(0.03*W[i][n][o][k]).
//                    blocks [0,45) also zero bij (softmax(0) -> c=0.1).
//   blocks [800,3104): x fp32 [b][p] -> bf16 xbp[b][p] + xpb[p][b] (LDS transpose)
__global__ void k_prep(const float* __restrict__ x, const float* __restrict__ W,
                       u16* __restrict__ xbp, u16* __restrict__ xpb,
                       u16* __restrict__ Wt, float* __restrict__ bij){
  __shared__ float tile[32][36];
  int t = threadIdx.x, u = blockIdx.x;
  if (u < 800){
    if (u < 45) bij[u*256 + t] = 0.f;
    int q = u / 5, ic = u - (u/5)*5;
    int n = q >> 4, o = q & 15;
    int i = ic*256 + t;
    if (i < I_){
      const float* src = W + (size_t)i*1280 + n*128 + o*8;
      float4 a = *reinterpret_cast<const float4*>(src);
      float4 b = *reinterpret_cast<const float4*>(src + 4);
      float vv[8] = {a.x,a.y,a.z,a.w,b.x,b.y,b.z,b.w};
      #pragma unroll
      for (int k = 0; k < 8; ++k)
        Wt[(size_t)q*P_ + (size_t)k*I_ + i] = f2bf(vv[k] * 0.03f);
    }
  } else {
    int b2 = u - 800;
    int tb = b2 & 7, tp = b2 >> 3;
    int b0 = tb << 5, p0 = tp << 5;
    int r = t >> 3, c4 = (t & 7) << 2;
    float4 v = *reinterpret_cast<const float4*>(x + (size_t)(b0 + r)*P_ + p0 + c4);
    *reinterpret_cast<float4*>(&tile[r][c4]) = v;
    uint2 pk;
    pk.x = (unsigned)f2bf(v.x) | ((unsigned)f2bf(v.y) << 16);
    pk.y = (unsigned)f2bf(v.z) | ((unsigned)f2bf(v.w) << 16);
    *reinterpret_cast<uint2*>(xbp + (size_t)(b0 + r)*P_ + p0 + c4) = pk;
    __syncthreads();
    float f0 = tile[c4+0][r], f1 = tile[c4+1][r], f2 = tile[c4+2][r], f3 = tile[c4+3][r];
    uint2 pk2;
    pk2.x = (unsigned)f2bf(f0) | ((unsigned)f2bf(f1) << 16);
    pk2.y = (unsigned)f2bf(f2) | ((unsigned)f2bf(f3) << 16);
    *reinterpret_cast<uint2*>(xpb + (size_t)(p0 + r)*B_ + b0 + c4) = pk2;
  }
}

// ---------------------------------------------------------------------------
// k_s2: GEMM-S with in-LDS softmax + B-scaling, n-PAIRED (R10): each block
// stages B for two adjacent n and runs both against the same A fragments —
// halves chip-wide A traffic (was 10 n-blocks re-reading each A slice).
// grid (8,5,16) x 128 = 640 blocks, 2 waves each.
// Block: b-pair bx2 (wave w owns b0 = bx2*32+w*16), n-pair np, K-chunk kc
// (576 p; i-range = (kc&1)*576 + [0,576), never spans k).
// Phase 1: one softmax per i, keep components 2np and 2np+1.
// Phase 2: Bt[nn][r][col] = bf16(bf2f(Wt[(2np+nn)*16+r][kc*576+col])*c2[nn][col])
//          — 2304 uint4 units (2 x 16 x 72), 18 per thread.
// Phase 3: 9 dual-acc MFMA steps x 2 n (A loaded once, 4 accumulators).
// Row pad 592: row stride 1184 B = 74*16 (ds_read_b128 aligned), 4-way worst
// bank aliasing (vs 8-way at 584).
__global__ __launch_bounds__(128) void k_s2(
    const u16* __restrict__ xbp, const u16* __restrict__ Wt,
    const float* __restrict__ bij, float* __restrict__ s_part){
  __shared__ u16  Bt[2][16][592];       // 37 KB
  __shared__ float c2[2][576];          // 4.5 KB
  int t = threadIdx.x;
  int bx2 = blockIdx.x, np = blockIdx.y, kc = blockIdx.z;
  int i0 = (kc & 1) * 576;

  // phase 1: softmax; keep components n=2np and n=2np+1
  for (int j = t; j < 576; j += 128){
    const float* br = bij + (size_t)(i0 + j)*N_;
    float l0 = br[0], l1 = br[1], l2 = br[2], l3 = br[3], l4 = br[4];
    float l5 = br[5], l6 = br[6], l7 = br[7], l8 = br[8], l9 = br[9];
    float mx = fmaxf(fmaxf(fmaxf(fmaxf(l0,l1),fmaxf(l2,l3)),
                           fmaxf(fmaxf(l4,l5),fmaxf(l6,l7))), fmaxf(l8,l9));
    float e0=__expf(l0-mx), e1=__expf(l1-mx), e2=__expf(l2-mx), e3=__expf(l3-mx), e4=__expf(l4-mx);
    float e5=__expf(l5-mx), e6=__expf(l6-mx), e7=__expf(l7-mx), e8=__expf(l8-mx), e9=__expf(l9-mx);
    float se = e0+e1+e2+e3+e4+e5+e6+e7+e8+e9;
    float inv = 1.f / se;
    float ev[10] = {e0,e1,e2,e3,e4,e5,e6,e7,e8,e9};
    c2[0][j] = ev[np*2]   * inv;
    c2[1][j] = ev[np*2+1] * inv;
  }
  __syncthreads();

  // phase 2: stage 2 scaled B-tiles — 2304 uint4 units (2 n x 16 r x 72), 18/thread
  for (int u = t; u < 2304; u += 128){
    int nn = u / 1152, rem = u - nn*1152;
    int r = rem / 72, cb = (rem - r*72) * 8;
    int q = (np*2 + nn)*16 + r;
    uint4 w = *reinterpret_cast<const uint4*>(Wt + (size_t)q*P_ + kc*576 + cb);
    float4 c0 = *reinterpret_cast<const float4*>(&c2[nn][cb]);
    float4 c1 = *reinterpret_cast<const float4*>(&c2[nn][cb + 4]);
    uint4 rr;
    rr.x = (unsigned)f2bf(bf2f(w.x & 0xffff)*c0.x) | ((unsigned)f2bf(bf2f(w.x >> 16)*c0.y) << 16);
    rr.y = (unsigned)f2bf(bf2f(w.y & 0xffff)*c0.z) | ((unsigned)f2bf(bf2f(w.y >> 16)*c0.w) << 16);
    rr.z = (unsigned)f2bf(bf2f(w.z & 0xffff)*c1.x) | ((unsigned)f2bf(bf2f(w.z >> 16)*c1.y) << 16);
    rr.w = (unsigned)f2bf(bf2f(w.w & 0xffff)*c1.z) | ((unsigned)f2bf(bf2f(w.w >> 16)*c1.w) << 16);
    *reinterpret_cast<uint4*>(&Bt[nn][r][cb]) = rr;
  }
  __syncthreads();

  // phase 3: MFMA, 9 dual-acc steps x 2 n; A loaded once per step
  int w = t >> 6, l = t & 63;
  int lo = l & 15, quad = l >> 4;
  int b0 = bx2*32 + w*16;
  const s8v* ap = reinterpret_cast<const s8v*>(xbp + (size_t)(b0 + lo)*P_ + kc*576 + quad*8);
  f4v a00 = {0.f,0.f,0.f,0.f}, a01 = {0.f,0.f,0.f,0.f};
  f4v a10 = {0.f,0.f,0.f,0.f}, a11 = {0.f,0.f,0.f,0.f};
  #pragma unroll
  for (int s = 0; s < 9; ++s){
    s8v av0 = ap[8*s];
    s8v av1 = ap[8*s + 4];
    s8v b00 = *reinterpret_cast<const s8v*>(&Bt[0][lo][quad*8 + 64*s]);
    s8v b01 = *reinterpret_cast<const s8v*>(&Bt[0][lo][quad*8 + 64*s + 32]);
    s8v b10 = *reinterpret_cast<const s8v*>(&Bt[1][lo][quad*8 + 64*s]);
    s8v b11 = *reinterpret_cast<const s8v*>(&Bt[1][lo][quad*8 + 64*s + 32]);
    a00 = __builtin_amdgcn_mfma_f32_16x16x32_bf16(av0, b00, a00, 0, 0, 0);
    a01 = __builtin_amdgcn_mfma_f32_16x16x32_bf16(av1, b01, a01, 0, 0, 0);
    a10 = __builtin_amdgcn_mfma_f32_16x16x32_bf16(av0, b10, a10, 0, 0, 0);
    a11 = __builtin_amdgcn_mfma_f32_16x16x32_bf16(av1, b11, a11, 0, 0, 0);
  }
  f4v accA = a00 + a01;
  f4v accB = a10 + a11;
  float* op = s_part + (size_t)kc*40960;
  int r0 = quad << 2;
  #pragma unroll
  for (int r = 0; r < 4; ++r){
    op[(size_t)(b0 + r0 + r)*NO_ + (np*2+0)*16 + lo] = accA[r];
    op[(size_t)(b0 + r0 + r)*NO_ + (np*2+1)*16 + lo] = accB[r];
  }
}

// ---------------------------------------------------------------------------
// k_sq: reduce 16 split-K partials, squash over O per (b,n) row, write fp32
// out and bf16 v^T[q][b]. grid 160 x 256. (unchanged)
__global__ void k_sq(const float* __restrict__ s_part, float* __restrict__ out,
                     u16* __restrict__ vbt){
  int t = threadIdx.x;
  int o = t & 15, rl = t >> 4;
  int rowid = blockIdx.x*16 + rl;          // b*10+n
  int b = rowid / 10, n = rowid - b*10;
  size_t idx = (size_t)b*NO_ + n*16 + o;
  float sv = 0.f;
  #pragma unroll
  for (int c = 0; c < 16; ++c) sv += s_part[idx + (size_t)c*40960];
  float sq = sv * sv;
  #pragma unroll
  for (int m = 8; m >= 1; m >>= 1) sq += __shfl_xor(sq, m, 16);
  float outv = sv * sqrtf(sq) / (1.0f + sq);
  out[idx] = outv;                         // final iteration's write survives
  vbt[(size_t)(n*16 + o)*B_ + b] = f2bf(outv);
}

// ---------------------------------------------------------------------------
// k_g: G[p][q] = sum_b xpb[p][b]*vbt[q][b] (never materialized); multiply by
// Wt fragment in-register, shuffle-sum over o-lanes, atomicAdd into bij[i][n]
// (accumulates across iterations). grid 720 x 256. (unchanged)
__global__ void k_g(const u16* __restrict__ xpb, const u16* __restrict__ vbt,
                    const u16* __restrict__ Wt, float* __restrict__ bij){
  int w = blockIdx.x*4 + (threadIdx.x >> 6);
  int l = threadIdx.x & 63;
  int pt = w % 576, qp = w / 576;
  int p0 = pt << 4;
  int lo = l & 15, quad = l >> 4;
  const s8v* ap  = reinterpret_cast<const s8v*>(xpb + (size_t)(p0 + lo)*B_ + quad*8);
  const s8v* bp0 = reinterpret_cast<const s8v*>(vbt + (size_t)((qp*2+0)*16 + lo)*B_ + quad*8);
  const s8v* bp1 = reinterpret_cast<const s8v*>(vbt + (size_t)((qp*2+1)*16 + lo)*B_ + quad*8);
  f4v acc0 = {0.f,0.f,0.f,0.f}, acc1 = {0.f,0.f,0.f,0.f};
  #pragma unroll
  for (int s = 0; s < 8; ++s){
    s8v a  = ap[4*s];
    s8v b0 = bp0[4*s];
    s8v b1 = bp1[4*s];
    acc0 = __builtin_amdgcn_mfma_f32_16x16x32_bf16(a, b0, acc0, 0, 0, 0);
    acc1 = __builtin_amdgcn_mfma_f32_16x16x32_bf16(a, b1, acc1, 0, 0, 0);
  }
  int ib = p0 % 1152;                      // p-tile never spans k (1152%16==0)
  #pragma unroll
  for (int s = 0; s < 2; ++s){
    f4v acc = s ? acc1 : acc0;
    int n = qp*2 + s;
    const u16* wp = Wt + (size_t)(n*16 + lo)*P_ + p0 + (quad << 2);
    ushort4 w4 = *reinterpret_cast<const ushort4*>(wp);
    float v0 = acc[0]*bf2f(w4.x), v1 = acc[1]*bf2f(w4.y);
    float v2 = acc[2]*bf2f(w4.z), v3 = acc[3]*bf2f(w4.w);
    #pragma unroll
    for (int m = 8; m >= 1; m >>= 1){
      v0 += __shfl_xor(v0, m, 16);
      v1 += __shfl_xor(v1, m, 16);
      v2 += __shfl_xor(v2, m, 16);
      v3 += __shfl_xor(v3, m, 16);
    }
    if (lo == 0){
      int i = ib + (quad << 2);
      atomicAdd(&bij[(i+0)*N_ + n], v0 * (1.f/256.f));
      atomicAdd(&bij[(i+1)*N_ + n], v1 * (1.f/256.f));
      atomicAdd(&bij[(i+2)*N_ + n], v2 * (1.f/256.f));
      atomicAdd(&bij[(i+3)*N_ + n], v3 * (1.f/256.f));
    }
  }
}

// ---------------------------------------------------------------------------
extern "C" void kernel_launch(void* const* d_in, const int* in_sizes, int n_in,
                              void* d_out, int out_size, void* d_ws, size_t ws_size,
                              hipStream_t stream){
  (void)in_sizes; (void)n_in; (void)out_size; (void)ws_size;
  const float* x = (const float*)d_in[0];   // (256, 8, 1152)
  const float* W = (const float*)d_in[1];   // (1, 1152, 10, 16, 8)
  float* out = (float*)d_out;               // (256, 10, 16, 1) fp32

  float* s_part = (float*)d_ws;             // 16 * 40960 fp32
  float* bij    = s_part + 16*40960;        // 11520 fp32
  u16* xbp = (u16*)(bij + 11520);           // 2359296 bf16
  u16* xpb = xbp + 2359296;                 // 2359296
  u16* Wt  = xpb + 2359296;                 // 1474560
  u16* vbt = Wt  + 1474560;                 // 40960

  k_prep<<<3104, 256, 0, stream>>>(x, W, xbp, xpb, Wt, bij);
  for (int it = 0; it < 3; ++it){
    k_s2<<<dim3(8, 5, 16), 128, 0, stream>>>(xbp, Wt, bij, s_part);
    k_sq<<<160, 256, 0, stream>>>(s_part, out, vbt);
    if (it < 2)
      k_g<<<720, 256, 0, stream>>>(xpb, vbt, Wt, bij);
  }
}

// Round 11
// 132.708 us; speedup vs baseline: 1.1195x; 1.1195x over previous
//
#include <hip/hip_runtime.h>

#define B_   256
#define I_   1152
#define N_   10
#define P_   9216      // 8 * 1152
#define NO_  160       // 10 * 16

typedef unsigned short u16;
typedef short s8v __attribute__((ext_vector_type(8)));
typedef float f4v __attribute__((ext_vector_type(4)));

__device__ inline float bf2f(u16 u){
  unsigned v = ((unsigned)u) << 16; float f; __builtin_memcpy(&f, &v, 4); return f;
}
__device__ inline u16 f2bf(float f){
  unsigned b; __builtin_memcpy(&b, &f, 4);
  b += 0x7fffu + ((b >> 16) & 1u);   // RNE
  return (u16)(b >> 16);
}

// ---------------------------------------------------------------------------
// k_prep: grid 3104 x 256.
//   blocks [0,800):  W-part, one (q, i-chunk-of-256) per block. q=u/5, ic=u%5.
//                    Wt[q=n*16+o][p=k*1152+i] = bf16(0.03*W[i][n][o][k]).
//                    blocks [0,45) zero bij; blocks [45,205) zero sA.
//   blocks [800,3104): x fp32 [b][p] -> bf16 xbp[b][p] + xpb[p][b] (LDS transpose)
__global__ void k_prep(const float* __restrict__ x, const float* __restrict__ W,
                       u16* __restrict__ xbp, u16* __restrict__ xpb,
                       u16* __restrict__ Wt, float* __restrict__ bij,
                       float* __restrict__ sA){
  __shared__ float tile[32][36];
  int t = threadIdx.x, u = blockIdx.x;
  if (u < 800){
    if (u < 45) bij[u*256 + t] = 0.f;
    else if (u < 205) sA[(u - 45)*256 + t] = 0.f;
    int q = u / 5, ic = u - (u/5)*5;
    int n = q >> 4, o = q & 15;
    int i = ic*256 + t;
    if (i < I_){
      const float* src = W + (size_t)i*1280 + n*128 + o*8;
      float4 a = *reinterpret_cast<const float4*>(src);
      float4 b = *reinterpret_cast<const float4*>(src + 4);
      float vv[8] = {a.x,a.y,a.z,a.w,b.x,b.y,b.z,b.w};
      #pragma unroll
      for (int k = 0; k < 8; ++k)
        Wt[(size_t)q*P_ + (size_t)k*I_ + i] = f2bf(vv[k] * 0.03f);
    }
  } else {
    int b2 = u - 800;
    int tb = b2 & 7, tp = b2 >> 3;
    int b0 = tb << 5, p0 = tp << 5;
    int r = t >> 3, c4 = (t & 7) << 2;
    float4 v = *reinterpret_cast<const float4*>(x + (size_t)(b0 + r)*P_ + p0 + c4);
    *reinterpret_cast<float4*>(&tile[r][c4]) = v;
    uint2 pk;
    pk.x = (unsigned)f2bf(v.x) | ((unsigned)f2bf(v.y) << 16);
    pk.y = (unsigned)f2bf(v.z) | ((unsigned)f2bf(v.w) << 16);
    *reinterpret_cast<uint2*>(xbp + (size_t)(b0 + r)*P_ + p0 + c4) = pk;
    __syncthreads();
    float f0 = tile[c4+0][r], f1 = tile[c4+1][r], f2 = tile[c4+2][r], f3 = tile[c4+3][r];
    uint2 pk2;
    pk2.x = (unsigned)f2bf(f0) | ((unsigned)f2bf(f1) << 16);
    pk2.y = (unsigned)f2bf(f2) | ((unsigned)f2bf(f3) << 16);
    *reinterpret_cast<uint2*>(xpb + (size_t)(p0 + r)*B_ + b0 + c4) = pk2;
  }
}

// ---------------------------------------------------------------------------
// k_s2a: R9's k_s2 shape (proven fastest) with atomic split-K epilogue.
// grid (8,10,16) x 128 = 1280 blocks, 2 waves.
// Phase 1: c_lds[j] = softmax_n(bij[i0+j][:]), i0=(kc&1)*576.
// Phase 2: Bt[r][col] = bf16(bf2f(Wt)*c), 1152 uint4 units, 9/thread.
// Phase 3: 9 dual-acc MFMA steps (576 K); epilogue atomicAdd into s_cur[b][q]
//          (16 kc contenders per address). Also zeroes its 32-float slice of
//          s_next (consumed only at the NEXT s2a dispatch — safe ordering).
__global__ __launch_bounds__(128) void k_s2a(
    const u16* __restrict__ xbp, const u16* __restrict__ Wt,
    const float* __restrict__ bij, float* __restrict__ s_cur,
    float* __restrict__ s_next){
  __shared__ u16  Bt[16][592];          // 18.5 KB
  __shared__ float c_lds[576];
  int t = threadIdx.x;
  int bx2 = blockIdx.x, n = blockIdx.y, kc = blockIdx.z;
  int lin = bx2 + 8*n + 80*kc;          // 0..1279
  if (t < 32) s_next[lin*32 + t] = 0.f;
  int i0 = (kc & 1) * 576;

  for (int j = t; j < 576; j += 128){
    const float* br = bij + (size_t)(i0 + j)*N_;
    float l0 = br[0], l1 = br[1], l2 = br[2], l3 = br[3], l4 = br[4];
    float l5 = br[5], l6 = br[6], l7 = br[7], l8 = br[8], l9 = br[9];
    float mx = fmaxf(fmaxf(fmaxf(fmaxf(l0,l1),fmaxf(l2,l3)),
                           fmaxf(fmaxf(l4,l5),fmaxf(l6,l7))), fmaxf(l8,l9));
    float e0=__expf(l0-mx), e1=__expf(l1-mx), e2=__expf(l2-mx), e3=__expf(l3-mx), e4=__expf(l4-mx);
    float e5=__expf(l5-mx), e6=__expf(l6-mx), e7=__expf(l7-mx), e8=__expf(l8-mx), e9=__expf(l9-mx);
    float se = e0+e1+e2+e3+e4+e5+e6+e7+e8+e9;
    float ev[10] = {e0,e1,e2,e3,e4,e5,e6,e7,e8,e9};
    c_lds[j] = ev[n] / se;
  }
  __syncthreads();

  for (int u = t; u < 1152; u += 128){
    int r = u / 72, cb = (u - r*72) * 8;
    uint4 w = *reinterpret_cast<const uint4*>(Wt + (size_t)(n*16 + r)*P_ + kc*576 + cb);
    float4 c0 = *reinterpret_cast<const float4*>(&c_lds[cb]);
    float4 c1 = *reinterpret_cast<const float4*>(&c_lds[cb + 4]);
    uint4 rr;
    rr.x = (unsigned)f2bf(bf2f(w.x & 0xffff)*c0.x) | ((unsigned)f2bf(bf2f(w.x >> 16)*c0.y) << 16);
    rr.y = (unsigned)f2bf(bf2f(w.y & 0xffff)*c0.z) | ((unsigned)f2bf(bf2f(w.y >> 16)*c0.w) << 16);
    rr.z = (unsigned)f2bf(bf2f(w.z & 0xffff)*c1.x) | ((unsigned)f2bf(bf2f(w.z >> 16)*c1.y) << 16);
    rr.w = (unsigned)f2bf(bf2f(w.w & 0xffff)*c1.z) | ((unsigned)f2bf(bf2f(w.w >> 16)*c1.w) << 16);
    *reinterpret_cast<uint4*>(&Bt[r][cb]) = rr;
  }
  __syncthreads();

  int w = t >> 6, l = t & 63;
  int lo = l & 15, quad = l >> 4;
  int b0 = bx2*32 + w*16;
  const s8v* ap = reinterpret_cast<const s8v*>(xbp + (size_t)(b0 + lo)*P_ + kc*576 + quad*8);
  f4v acc0 = {0.f,0.f,0.f,0.f}, acc1 = {0.f,0.f,0.f,0.f};
  #pragma unroll
  for (int s = 0; s < 9; ++s){
    s8v a0 = ap[8*s];
    s8v b0v = *reinterpret_cast<const s8v*>(&Bt[lo][quad*8 + 64*s]);
    s8v a1 = ap[8*s + 4];
    s8v b1v = *reinterpret_cast<const s8v*>(&Bt[lo][quad*8 + 64*s + 32]);
    acc0 = __builtin_amdgcn_mfma_f32_16x16x32_bf16(a0, b0v, acc0, 0, 0, 0);
    acc1 = __builtin_amdgcn_mfma_f32_16x16x32_bf16(a1, b1v, acc1, 0, 0, 0);
  }
  f4v acc = acc0 + acc1;
  int r0 = quad << 2;
  #pragma unroll
  for (int r = 0; r < 4; ++r)
    atomicAdd(&s_cur[(size_t)(b0 + r0 + r)*NO_ + n*16 + lo], acc[r]);
}

// ---------------------------------------------------------------------------
// k_g2: squash-from-s prologue + GEMM-G + bij dot. grid 720 x 256.
// Block owns q-pair qp = bid/144; its 4 waves cover pt = (bid%144)*4+wv.
// Prologue: thread b recomputes v for its 2 n's from s[b][q] (16-f rows),
// writes bf16 to LDS vl[q_local][b] (row 264 u16: b128 reads conflict-free).
// Then MFMA over b-chunks (B-fragments from LDS), Wt product, 16-lane
// o-reduce, atomicAdd bij. vbt global buffer + k_sq dispatches eliminated.
__global__ __launch_bounds__(256, 4) void k_g2(
    const u16* __restrict__ xpb, const float* __restrict__ s,
    const u16* __restrict__ Wt, float* __restrict__ bij){
  __shared__ u16 vl[32][264];           // 16.5 KB
  int t = threadIdx.x;
  int qp = blockIdx.x / 144;
  int b = t;
  #pragma unroll
  for (int nn = 0; nn < 2; ++nn){
    const float* sr = s + (size_t)b*NO_ + (qp*2 + nn)*16;
    float4 s0 = *reinterpret_cast<const float4*>(sr);
    float4 s1 = *reinterpret_cast<const float4*>(sr + 4);
    float4 s2 = *reinterpret_cast<const float4*>(sr + 8);
    float4 s3 = *reinterpret_cast<const float4*>(sr + 12);
    float sq = s0.x*s0.x+s0.y*s0.y+s0.z*s0.z+s0.w*s0.w
             + s1.x*s1.x+s1.y*s1.y+s1.z*s1.z+s1.w*s1.w
             + s2.x*s2.x+s2.y*s2.y+s2.z*s2.z+s2.w*s2.w
             + s3.x*s3.x+s3.y*s3.y+s3.z*s3.z+s3.w*s3.w;
    float scale = sqrtf(sq) / (1.0f + sq);
    float sv[16] = {s0.x,s0.y,s0.z,s0.w,s1.x,s1.y,s1.z,s1.w,
                    s2.x,s2.y,s2.z,s2.w,s3.x,s3.y,s3.z,s3.w};
    #pragma unroll
    for (int o = 0; o < 16; ++o)
      vl[nn*16 + o][b] = f2bf(sv[o] * scale);
  }
  __syncthreads();

  int wv = t >> 6, l = t & 63;
  int pt = (blockIdx.x % 144)*4 + wv;
  int p0 = pt << 4;
  int lo = l & 15, quad = l >> 4;
  const s8v* ap = reinterpret_cast<const s8v*>(xpb + (size_t)(p0 + lo)*B_ + quad*8);
  f4v acc0 = {0.f,0.f,0.f,0.f}, acc1 = {0.f,0.f,0.f,0.f};
  #pragma unroll
  for (int st = 0; st < 8; ++st){
    s8v a  = ap[4*st];
    s8v b0 = *reinterpret_cast<const s8v*>(&vl[lo]     [st*32 + quad*8]);
    s8v b1 = *reinterpret_cast<const s8v*>(&vl[16 + lo][st*32 + quad*8]);
    acc0 = __builtin_amdgcn_mfma_f32_16x16x32_bf16(a, b0, acc0, 0, 0, 0);
    acc1 = __builtin_amdgcn_mfma_f32_16x16x32_bf16(a, b1, acc1, 0, 0, 0);
  }
  int ib = p0 % 1152;                   // p-tile never spans k (1152%16==0)
  #pragma unroll
  for (int sb = 0; sb < 2; ++sb){
    f4v acc = sb ? acc1 : acc0;
    int n = qp*2 + sb;
    const u16* wp = Wt + (size_t)(n*16 + lo)*P_ + p0 + (quad << 2);
    ushort4 w4 = *reinterpret_cast<const ushort4*>(wp);
    float v0 = acc[0]*bf2f(w4.x), v1 = acc[1]*bf2f(w4.y);
    float v2 = acc[2]*bf2f(w4.z), v3 = acc[3]*bf2f(w4.w);
    #pragma unroll
    for (int m = 8; m >= 1; m >>= 1){
      v0 += __shfl_xor(v0, m, 16);
      v1 += __shfl_xor(v1, m, 16);
      v2 += __shfl_xor(v2, m, 16);
      v3 += __shfl_xor(v3, m, 16);
    }
    if (lo == 0){
      int i = ib + (quad << 2);
      atomicAdd(&bij[(i+0)*N_ + n], v0 * (1.f/256.f));
      atomicAdd(&bij[(i+1)*N_ + n], v1 * (1.f/256.f));
      atomicAdd(&bij[(i+2)*N_ + n], v2 * (1.f/256.f));
      atomicAdd(&bij[(i+3)*N_ + n], v3 * (1.f/256.f));
    }
  }
}

// ---------------------------------------------------------------------------
// k_sqout: final squash, s[b][q] -> out fp32. grid 160 x 256.
__global__ void k_sqout(const float* __restrict__ s, float* __restrict__ out){
  int t = threadIdx.x;
  int o = t & 15, rl = t >> 4;
  int rowid = blockIdx.x*16 + rl;          // b*10+n
  int b = rowid / 10, n = rowid - b*10;
  size_t idx = (size_t)b*NO_ + n*16 + o;
  float sv = s[idx];
  float sq = sv * sv;
  #pragma unroll
  for (int m = 8; m >= 1; m >>= 1) sq += __shfl_xor(sq, m, 16);
  out[idx] = sv * sqrtf(sq) / (1.0f + sq);
}

// ---------------------------------------------------------------------------
extern "C" void kernel_launch(void* const* d_in, const int* in_sizes, int n_in,
                              void* d_out, int out_size, void* d_ws, size_t ws_size,
                              hipStream_t stream){
  (void)in_sizes; (void)n_in; (void)out_size; (void)ws_size;
  const float* x = (const float*)d_in[0];   // (256, 8, 1152)
  const float* W = (const float*)d_in[1];   // (1, 1152, 10, 16, 8)
  float* out = (float*)d_out;               // (256, 10, 16, 1) fp32

  float* sA  = (float*)d_ws;                // 40960 fp32
  float* sB  = sA + 40960;                  // 40960
  float* bij = sB + 40960;                  // 11520
  u16* xbp = (u16*)(bij + 11520);           // 2359296 bf16
  u16* xpb = xbp + 2359296;                 // 2359296
  u16* Wt  = xpb + 2359296;                 // 1474560

  k_prep<<<3104, 256, 0, stream>>>(x, W, xbp, xpb, Wt, bij, sA);
  // ping-pong: iter0 -> sA (sB zeroed), iter1 -> sB (sA zeroed), iter2 -> sA
  k_s2a<<<dim3(8, 10, 16), 128, 0, stream>>>(xbp, Wt, bij, sA, sB);
  k_g2 <<<720, 256, 0, stream>>>(xpb, sA, Wt, bij);
  k_s2a<<<dim3(8, 10, 16), 128, 0, stream>>>(xbp, Wt, bij, sB, sA);
  k_g2 <<<720, 256, 0, stream>>>(xpb, sB, Wt, bij);
  k_s2a<<<dim3(8, 10, 16), 128, 0, stream>>>(xbp, Wt, bij, sA, sB);
  k_sqout<<<160, 256, 0, stream>>>(sA, out);
}